// Round 6
// baseline (63.571 us; speedup 1.0000x reference)
//
#include <hip/hip_runtime.h>

#define N_NODES 30000
#define C 128
#define E_EDGES 480000
#define BM 64

typedef __attribute__((ext_vector_type(8))) short bf16x8;
typedef __attribute__((ext_vector_type(4))) float f32x4;

// ws layout:
//   bytes  [0, 131072)                : Bt bf16 [set][256 cols][128 k]
//   float  32768 + set*256            : cv f32 [set][256]
//   float  33280 + g*N_NODES          : masks f32, g: 0=graph1,1=graph21,2=graph2,3=graph12
//   shorts 306688 + set*3840000       : fbf bf16 [set][30000][128]  (byte 613376)
#define CV_OFF_F(set) (32768 + (set) * 256)
#define MASK_OFF_F(g) (33280 + (g) * N_NODES)
#define FBF_OFF_S(set) (306688 + (size_t)(set) * (N_NODES * C))

#define PREP_BLKS 128
#define ZERO_BLKS 235              // 235*256 >= 2*N_NODES
#define CVT_BLKS  1875             // 1875*2048 == N_NODES*C
__device__ __forceinline__ unsigned short f2bf(float f) {
  union { float f; unsigned int u; } v; v.f = f;
  unsigned int r = v.u + 0x7FFF + ((v.u >> 16) & 1);  // RNE
  return (unsigned short)(r >> 16);
}

// ---------------------------------------------------------------------------
// K1: fused prep (x<128) + mask zeroing (x<128+235) + feat f32->bf16 cvt (rest)
// grid (128+235+1875, 2), block 256
// ---------------------------------------------------------------------------
__global__ void prep_zero_cvt_kernel(const float* __restrict__ wv1, const float* __restrict__ bv1,
                                     const float* __restrict__ wp1,
                                     const float* __restrict__ wv2, const float* __restrict__ bv2,
                                     const float* __restrict__ wp2,
                                     const float* __restrict__ feat1, const float* __restrict__ feat2,
                                     float* __restrict__ ws) {
  const int set = blockIdx.y;
  const int bx = blockIdx.x;
  const int t = threadIdx.x;

  if (bx >= PREP_BLKS + ZERO_BLKS) {
    // ---- cvt: 2048 elements per block ----
    const int bidc = bx - (PREP_BLKS + ZERO_BLKS);
    const size_t base = (size_t)bidc * 2048 + (size_t)t * 8;
    const float* feat = set ? feat2 : feat1;
    const float4 v0 = *reinterpret_cast<const float4*>(feat + base);
    const float4 v1 = *reinterpret_cast<const float4*>(feat + base + 4);
    bf16x8 o;
    o[0] = (short)f2bf(v0.x); o[1] = (short)f2bf(v0.y);
    o[2] = (short)f2bf(v0.z); o[3] = (short)f2bf(v0.w);
    o[4] = (short)f2bf(v1.x); o[5] = (short)f2bf(v1.y);
    o[6] = (short)f2bf(v1.z); o[7] = (short)f2bf(v1.w);
    unsigned short* fbf = (unsigned short*)ws + FBF_OFF_S(set);
    *reinterpret_cast<bf16x8*>(fbf + base) = o;
    return;
  }
  if (bx >= PREP_BLKS) {
    const int idx = (bx - PREP_BLKS) * 256 + t;
    if (idx < 2 * N_NODES) ws[33280 + set * 2 * N_NODES + idx] = 0.f;
    return;
  }
  // ---- prep ----
  const int k = bx;  // 0..127
  const float* wv = set ? wv2 : wv1;
  const float* bv = set ? bv2 : bv1;
  const float* wp = set ? wp2 : wp1;

  __shared__ float wvcol[C];
  if (t < C) wvcol[t] = wv[t * C + k];
  __syncthreads();

  const int j = t;  // 0..255
  const float* wprow = wp + (j & 127) * (2 * C) + ((j < C) ? 0 : C);
  float s = 0.f;
#pragma unroll 4
  for (int c = 0; c < C; ++c) s += wvcol[c] * wprow[c];
  unsigned short* bt = (unsigned short*)ws;
  bt[set * 32768 + j * 128 + k] = f2bf(s);

  if (k == 0) {
    float s2 = 0.f;
#pragma unroll 4
    for (int c = 0; c < C; ++c) s2 += bv[c] * wprow[c];
    ws[CV_OFF_F(set) + j] = s2;
  }
}

// ---------------------------------------------------------------------------
// K2: scatter membership masks
// ---------------------------------------------------------------------------
__global__ void scatter_masks(const int* __restrict__ g1, const int* __restrict__ g21,
                              const int* __restrict__ g2, const int* __restrict__ g12,
                              float* __restrict__ ws) {
  const int e = blockIdx.x * 256 + threadIdx.x;
  if (e >= E_EDGES) return;
  const int g = blockIdx.y;
  const int* gp = (g == 0) ? g1 : (g == 1) ? g21 : (g == 2) ? g2 : g12;
  ws[MASK_OFF_F(g) + gp[e]] = 1.0f;  // idempotent
}

// ---------------------------------------------------------------------------
// K3: barrier-free, LDS-free main.
//   A: bf16x8 gathers from precomputed bf16 feat (block footprint 16 KB -> L1).
//   B: 16 bf16x8 upfront from Bt (L2-resident).
//   MFMA swapped: acc = mfma(b, a, acc) -> lane owns row i, 4 consecutive jj.
// grid (ceil(N/64), 2), block 512 (8 waves = 2M x 4J).
// ---------------------------------------------------------------------------
__global__ __launch_bounds__(512, 4) void main_kernel(
    const float* __restrict__ bp1, const float* __restrict__ bp2,
    const float* __restrict__ ws, float* __restrict__ out) {
  const int set = blockIdx.y;
  const float* bp   = set ? bp2 : bp1;
  const unsigned short* Bt = (const unsigned short*)ws + (size_t)set * 32768;
  const unsigned short* fbf = (const unsigned short*)ws + FBF_OFF_S(set);
  const float* cv = ws + CV_OFF_F(set);
  const float* mA = ws + MASK_OFF_F(2 * set);
  const float* mB = ws + MASK_OFF_F(2 * set + 1);
  float* outp = out + (size_t)set * N_NODES * C;

  const int i0 = blockIdx.x * BM;
  const int tid = threadIdx.x;
  const int wave = tid >> 6;   // 0..7
  const int lane = tid & 63;
  const int wm = wave >> 2;    // 0..1 -> rows [wm*32, +32)
  const int wj = wave & 3;     // 0..3 -> jj   [wj*32, +32)
  const int l15 = lane & 15;
  const int lk  = lane >> 4;   // 0..3

  // ---- all 16 B fragments (64 VGPR) from L2 ----
  const unsigned short* bb = Bt + (size_t)(wj * 32 + l15) * 128 + lk * 8;
  bf16x8 breg[4][2][2];  // [ks][nt][h]
#pragma unroll
  for (int ks = 0; ks < 4; ++ks)
#pragma unroll
    for (int nt = 0; nt < 2; ++nt)
#pragma unroll
      for (int h = 0; h < 2; ++h)
        breg[ks][nt][h] =
            *reinterpret_cast<const bf16x8*>(bb + (nt * 16 + h * 128) * 128 + ks * 32);

  // ---- A row pointers (clamped; OOB rows never stored) ----
  const unsigned short* arow[2];
#pragma unroll
  for (int mt = 0; mt < 2; ++mt) {
    int gi = i0 + wm * 32 + mt * 16 + l15;
    if (gi >= N_NODES) gi = N_NODES - 1;
    arow[mt] = fbf + (size_t)gi * C + lk * 8;
  }

  f32x4 acc[2][2][2] = {};     // [mt][nt][h]

#pragma unroll
  for (int ks = 0; ks < 4; ++ks) {
    bf16x8 a[2];
#pragma unroll
    for (int mt = 0; mt < 2; ++mt)
      a[mt] = *reinterpret_cast<const bf16x8*>(arow[mt] + ks * 32);
#pragma unroll
    for (int mt = 0; mt < 2; ++mt)
#pragma unroll
      for (int nt = 0; nt < 2; ++nt)
#pragma unroll
        for (int h = 0; h < 2; ++h)
          acc[mt][nt][h] = __builtin_amdgcn_mfma_f32_16x16x32_bf16(
              breg[ks][nt][h], a[mt], acc[mt][nt][h], 0, 0, 0);  // swapped
  }

  // ---- epilogue: i = i0+wm*32+mt*16+l15 ; jj = wj*32+nt*16+lk*4+r ----
  const int jjb = wj * 32 + lk * 4;
#pragma unroll
  for (int mt = 0; mt < 2; ++mt) {
    const int i = i0 + wm * 32 + mt * 16 + l15;
    if (i >= N_NODES) continue;
    const float hA = mA[i];
    const float hB = mB[i];
#pragma unroll
    for (int nt = 0; nt < 2; ++nt) {
      const int jj4 = jjb + nt * 16;
      const float4 cvA = *reinterpret_cast<const float4*>(cv + jj4);
      const float4 cvB = *reinterpret_cast<const float4*>(cv + jj4 + 128);
      const float4 bp4 = *reinterpret_cast<const float4*>(bp + jj4);
      float4 o;
      o.x = hA * (acc[mt][nt][0][0] + cvA.x) + hB * (acc[mt][nt][1][0] + cvB.x) + bp4.x;
      o.y = hA * (acc[mt][nt][0][1] + cvA.y) + hB * (acc[mt][nt][1][1] + cvB.y) + bp4.y;
      o.z = hA * (acc[mt][nt][0][2] + cvA.z) + hB * (acc[mt][nt][1][2] + cvB.z) + bp4.z;
      o.w = hA * (acc[mt][nt][0][3] + cvA.w) + hB * (acc[mt][nt][1][3] + cvB.w) + bp4.w;
      *reinterpret_cast<float4*>(outp + (size_t)i * C + jj4) = o;
    }
  }
}

// ---------------------------------------------------------------------------
extern "C" void kernel_launch(void* const* d_in, const int* in_sizes, int n_in,
                              void* d_out, int out_size, void* d_ws, size_t ws_size,
                              hipStream_t stream) {
  const float* feat1 = (const float*)d_in[0];
  const float* feat2 = (const float*)d_in[2];
  const float* wv1 = (const float*)d_in[20];
  const float* bv1 = (const float*)d_in[21];
  const float* wv2 = (const float*)d_in[22];
  const float* bv2 = (const float*)d_in[23];
  const float* wp1 = (const float*)d_in[24];
  const float* bp1 = (const float*)d_in[25];
  const float* wp2 = (const float*)d_in[26];
  const float* bp2 = (const float*)d_in[27];
  const int* graph1  = (const int*)d_in[28];
  const int* graph2  = (const int*)d_in[29];
  const int* graph12 = (const int*)d_in[30];
  const int* graph21 = (const int*)d_in[31];

  float* ws = (float*)d_ws;
  float* out = (float*)d_out;

  prep_zero_cvt_kernel<<<dim3(PREP_BLKS + ZERO_BLKS + CVT_BLKS, 2), 256, 0, stream>>>(
      wv1, bv1, wp1, wv2, bv2, wp2, feat1, feat2, ws);
  scatter_masks<<<dim3((E_EDGES + 255) / 256, 4), 256, 0, stream>>>(graph1, graph21, graph2, graph12, ws);
  main_kernel<<<dim3((N_NODES + BM - 1) / BM, 2), 512, 0, stream>>>(bp1, bp2, ws, out);
}

// Round 7
// 48.293 us; speedup vs baseline: 1.3164x; 1.3164x over previous
//
#include <hip/hip_runtime.h>

#define N_NODES 30000
#define C 128
#define E_EDGES 480000
#define NT_TILES 469   // ceil(30000/64)

typedef __attribute__((ext_vector_type(8))) short bf16x8;
typedef __attribute__((ext_vector_type(4))) float f32x4;

// ws layout (float units unless noted):
//   bytes [0, 131072)        : Bt bf16 [set][256 cols][128 k]
//   float 32768 + set*256    : cv f32 [set][256]
//   float 33280 + g*N_NODES  : masks f32, g: 0=graph1,1=graph21,2=graph2,3=graph12
#define CV_OFF_F(set) (32768 + (set) * 256)
#define MASK_OFF_F(g) (33280 + (g) * N_NODES)

__device__ __forceinline__ unsigned short f2bf(float f) {
  union { float f; unsigned int u; } v; v.f = f;
  unsigned int r = v.u + 0x7FFF + ((v.u >> 16) & 1);  // RNE
  return (unsigned short)(r >> 16);
}

// ---------------------------------------------------------------------------
// K1: fused prep (x<128) + mask zeroing (x>=128). grid (128+235, 2), block 256
// ---------------------------------------------------------------------------
__global__ void prep_zero_kernel(const float* __restrict__ wv1, const float* __restrict__ bv1,
                                 const float* __restrict__ wp1,
                                 const float* __restrict__ wv2, const float* __restrict__ bv2,
                                 const float* __restrict__ wp2,
                                 float* __restrict__ ws) {
  const int set = blockIdx.y;
  if (blockIdx.x >= 128) {
    const int idx = (blockIdx.x - 128) * 256 + threadIdx.x;
    if (idx < 2 * N_NODES) ws[33280 + set * 2 * N_NODES + idx] = 0.f;
    return;
  }
  const int k = blockIdx.x;  // 0..127
  const float* wv = set ? wv2 : wv1;
  const float* bv = set ? bv2 : bv1;
  const float* wp = set ? wp2 : wp1;

  __shared__ float wvcol[C];
  const int t = threadIdx.x;
  if (t < C) wvcol[t] = wv[t * C + k];
  __syncthreads();

  const int j = t;  // 0..255
  const float* wprow = wp + (j & 127) * (2 * C) + ((j < C) ? 0 : C);
  float s = 0.f;
#pragma unroll 4
  for (int c = 0; c < C; ++c) s += wvcol[c] * wprow[c];
  unsigned short* bt = (unsigned short*)ws;
  bt[set * 32768 + j * 128 + k] = f2bf(s);

  if (k == 0) {
    float s2 = 0.f;
#pragma unroll 4
    for (int c = 0; c < C; ++c) s2 += bv[c] * wprow[c];
    ws[CV_OFF_F(set) + j] = s2;
  }
}

// ---------------------------------------------------------------------------
// K2: scatter membership masks, int4-vectorized edge reads
// grid ((E/4+255)/256, 4), block 256
// ---------------------------------------------------------------------------
__global__ void scatter_masks(const int* __restrict__ g1, const int* __restrict__ g21,
                              const int* __restrict__ g2, const int* __restrict__ g12,
                              float* __restrict__ ws) {
  const int e4 = blockIdx.x * 256 + threadIdx.x;
  if (e4 >= E_EDGES / 4) return;
  const int g = blockIdx.y;
  const int* gp = (g == 0) ? g1 : (g == 1) ? g21 : (g == 2) ? g2 : g12;
  const int4 v = reinterpret_cast<const int4*>(gp)[e4];
  float* m = ws + MASK_OFF_F(g);
  m[v.x] = 1.0f; m[v.y] = 1.0f; m[v.z] = 1.0f; m[v.w] = 1.0f;  // idempotent
}

// ---------------------------------------------------------------------------
// K3: persistent-B multi-tile main.
//   - B staged into LDS ONCE per block (64 KB, coalesced, XOR-swizzled)
//   - loop over 1-2 row-tiles (chunked): T14 split A-staging (issue next-tile
//     global f32 loads before compute; cvt+ds_write after barrier)
//   - MFMA swapped: acc = mfma(b, a, acc) -> lane owns row i, 4 consecutive jj
// grid (256, 2), block 512 (8 waves = 2M x 4J). LDS 80 KB -> 2 blocks/CU.
// ---------------------------------------------------------------------------
__global__ __launch_bounds__(512, 4) void main_kernel(
    const float* __restrict__ feat1, const float* __restrict__ feat2,
    const float* __restrict__ bp1, const float* __restrict__ bp2,
    const float* __restrict__ ws, float* __restrict__ out) {
  const int set = blockIdx.y;
  const int bx = blockIdx.x;  // 0..255
  const float* feat = set ? feat2 : feat1;
  const float* bp   = set ? bp2 : bp1;
  const unsigned short* Bt = (const unsigned short*)ws + (size_t)set * 32768;
  const float* cv = ws + CV_OFF_F(set);
  const float* mA = ws + MASK_OFF_F(2 * set);
  const float* mB = ws + MASK_OFF_F(2 * set + 1);
  float* outp = out + (size_t)set * N_NODES * C;

  // chunked tile range: q=1, r=213 for 256 blocks over 469 tiles
  const int q = NT_TILES >> 8;          // 1
  const int r = NT_TILES - (q << 8);    // 213
  const int t0  = bx * q + (bx < r ? bx : r);
  const int cnt = q + (bx < r ? 1 : 0);

  __shared__ unsigned short bt_s[256 * 128];  // 64 KB
  __shared__ unsigned short feat_s[64 * 128]; // 16 KB

  const int tid = threadIdx.x;
  const int wave = tid >> 6;
  const int lane = tid & 63;
  const int wm = wave >> 2;    // 0..1
  const int wj = wave & 3;     // 0..3
  const int l15 = lane & 15;
  const int lk  = lane >> 4;   // 0..3

  // ---- stage B once: 4096 float4, coalesced, swizzled ----
  const float4* btsrc = reinterpret_cast<const float4*>(Bt);
#pragma unroll
  for (int l = 0; l < 8; ++l) {
    const int idx = tid + 512 * l;       // 0..4095
    const float4 v = btsrc[idx];
    int byte = idx * 16;
    byte ^= (((byte >> 8) & 7) << 4);
    *reinterpret_cast<float4*>(reinterpret_cast<char*>(bt_s) + byte) = v;
  }

  // ---- hoist col-side constants: jj4 = wj*32 + lk*4 + nt*16 ----
  const int jjb = wj * 32 + lk * 4;
  float4 cvA[2], cvB[2], bpv[2];
#pragma unroll
  for (int nt = 0; nt < 2; ++nt) {
    const int jj4 = jjb + nt * 16;
    cvA[nt] = *reinterpret_cast<const float4*>(cv + jj4);
    cvB[nt] = *reinterpret_cast<const float4*>(cv + jj4 + 128);
    bpv[nt] = *reinterpret_cast<const float4*>(bp + jj4);
  }

  // ---- prologue: stage A tile t0 ----
#pragma unroll
  for (int l = 0; l < 4; ++l) {
    const int idx = tid + 512 * l;       // 0..2047
    const int rr = idx >> 5;
    const int qq = idx & 31;
    int gi = t0 * 64 + rr;
    if (gi >= N_NODES) gi = N_NODES - 1;
    const float4 v = reinterpret_cast<const float4*>(feat + (size_t)gi * C)[qq];
    ushort4 h4;
    h4.x = f2bf(v.x); h4.y = f2bf(v.y); h4.z = f2bf(v.z); h4.w = f2bf(v.w);
    int byte = rr * 256 + qq * 8;
    byte ^= ((rr & 7) << 4);
    *reinterpret_cast<ushort4*>(reinterpret_cast<char*>(feat_s) + byte) = h4;
  }
  __syncthreads();

  for (int k = 0; k < cnt; ++k) {
    const int t = t0 + k;
    const bool hasNext = (k + 1 < cnt);

    // ---- T14: issue next-tile global loads now (latency hides under MFMA) ----
    float4 pre[4];
    if (hasNext) {
#pragma unroll
      for (int l = 0; l < 4; ++l) {
        const int idx = tid + 512 * l;
        const int rr = idx >> 5;
        const int qq = idx & 31;
        int gi = (t + 1) * 64 + rr;
        if (gi >= N_NODES) gi = N_NODES - 1;
        pre[l] = reinterpret_cast<const float4*>(feat + (size_t)gi * C)[qq];
      }
    }

    // ---- prefetch masks for this tile ----
    const int i0 = t * 64;
    int irow[2];
    float hA[2], hB[2];
#pragma unroll
    for (int mt = 0; mt < 2; ++mt) {
      const int i = i0 + wm * 32 + mt * 16 + l15;
      irow[mt] = i;
      const int ic = (i < N_NODES) ? i : (N_NODES - 1);
      hA[mt] = mA[ic];
      hB[mt] = mB[ic];
    }

    // ---- compute tile t from LDS ----
    f32x4 acc[2][2][2] = {};
#pragma unroll
    for (int ks = 0; ks < 4; ++ks) {
      bf16x8 a[2];
#pragma unroll
      for (int mt = 0; mt < 2; ++mt) {
        const int row = wm * 32 + mt * 16 + l15;
        int byte = row * 256 + ks * 64 + lk * 16;
        byte ^= ((row & 7) << 4);
        a[mt] = *reinterpret_cast<const bf16x8*>(reinterpret_cast<const char*>(feat_s) + byte);
      }
      bf16x8 b_[2][2];
#pragma unroll
      for (int nt = 0; nt < 2; ++nt)
#pragma unroll
        for (int h = 0; h < 2; ++h) {
          const int col = wj * 32 + nt * 16 + h * 128 + l15;
          int byte = col * 256 + ks * 64 + lk * 16;
          byte ^= ((col & 7) << 4);
          b_[nt][h] = *reinterpret_cast<const bf16x8*>(reinterpret_cast<const char*>(bt_s) + byte);
        }
#pragma unroll
      for (int mt = 0; mt < 2; ++mt)
#pragma unroll
        for (int nt = 0; nt < 2; ++nt)
#pragma unroll
          for (int h = 0; h < 2; ++h)
            acc[mt][nt][h] = __builtin_amdgcn_mfma_f32_16x16x32_bf16(
                b_[nt][h], a[mt], acc[mt][nt][h], 0, 0, 0);  // swapped
    }

    // ---- epilogue ----
#pragma unroll
    for (int mt = 0; mt < 2; ++mt) {
      if (irow[mt] >= N_NODES) continue;
#pragma unroll
      for (int nt = 0; nt < 2; ++nt) {
        const int jj4 = jjb + nt * 16;
        float4 o;
        o.x = hA[mt] * (acc[mt][nt][0][0] + cvA[nt].x) + hB[mt] * (acc[mt][nt][1][0] + cvB[nt].x) + bpv[nt].x;
        o.y = hA[mt] * (acc[mt][nt][0][1] + cvA[nt].y) + hB[mt] * (acc[mt][nt][1][1] + cvB[nt].y) + bpv[nt].y;
        o.z = hA[mt] * (acc[mt][nt][0][2] + cvA[nt].z) + hB[mt] * (acc[mt][nt][1][2] + cvB[nt].z) + bpv[nt].z;
        o.w = hA[mt] * (acc[mt][nt][0][3] + cvA[nt].w) + hB[mt] * (acc[mt][nt][1][3] + cvB[nt].w) + bpv[nt].w;
        *reinterpret_cast<float4*>(outp + (size_t)irow[mt] * C + jj4) = o;
      }
    }

    // ---- write prefetched tile into LDS for next iteration ----
    if (hasNext) {
      __syncthreads();  // all waves done reading feat_s
#pragma unroll
      for (int l = 0; l < 4; ++l) {
        const int idx = tid + 512 * l;
        const int rr = idx >> 5;
        const int qq = idx & 31;
        ushort4 h4;
        h4.x = f2bf(pre[l].x); h4.y = f2bf(pre[l].y);
        h4.z = f2bf(pre[l].z); h4.w = f2bf(pre[l].w);
        int byte = rr * 256 + qq * 8;
        byte ^= ((rr & 7) << 4);
        *reinterpret_cast<ushort4*>(reinterpret_cast<char*>(feat_s) + byte) = h4;
      }
      __syncthreads();
    }
  }
}

// ---------------------------------------------------------------------------
extern "C" void kernel_launch(void* const* d_in, const int* in_sizes, int n_in,
                              void* d_out, int out_size, void* d_ws, size_t ws_size,
                              hipStream_t stream) {
  const float* feat1 = (const float*)d_in[0];
  const float* feat2 = (const float*)d_in[2];
  const float* wv1 = (const float*)d_in[20];
  const float* bv1 = (const float*)d_in[21];
  const float* wv2 = (const float*)d_in[22];
  const float* bv2 = (const float*)d_in[23];
  const float* wp1 = (const float*)d_in[24];
  const float* bp1 = (const float*)d_in[25];
  const float* wp2 = (const float*)d_in[26];
  const float* bp2 = (const float*)d_in[27];
  const int* graph1  = (const int*)d_in[28];
  const int* graph2  = (const int*)d_in[29];
  const int* graph12 = (const int*)d_in[30];
  const int* graph21 = (const int*)d_in[31];

  float* ws = (float*)d_ws;
  float* out = (float*)d_out;

  prep_zero_kernel<<<dim3(128 + 235, 2), 256, 0, stream>>>(wv1, bv1, wp1, wv2, bv2, wp2, ws);
  scatter_masks<<<dim3((E_EDGES / 4 + 255) / 256, 4), 256, 0, stream>>>(
      graph1, graph21, graph2, graph12, ws);
  main_kernel<<<dim3(256, 2), 512, 0, stream>>>(feat1, feat2, bp1, bp2, ws, out);
}